// Round 2
// baseline (722.067 us; speedup 1.0000x reference)
//
#include <hip/hip_runtime.h>
#include <hip/hip_bf16.h>

typedef __attribute__((ext_vector_type(8))) short short8;
typedef __attribute__((ext_vector_type(4))) short short4v;
typedef __attribute__((ext_vector_type(4))) float f32x4;
typedef unsigned short u16;

// ---- bf16 helpers (bit-level, RNE) ----
__device__ inline float b2f(u16 u) {
    unsigned int i = ((unsigned int)u) << 16;
    float f; __builtin_memcpy(&f, &i, 4); return f;
}
__device__ inline u16 f2b(float f) {
    unsigned int i; __builtin_memcpy(&i, &f, 4);
    unsigned int r = (i + 0x7FFFu + ((i >> 16) & 1u)) >> 16;
    return (u16)r;
}

#define GLDS(g, l) __builtin_amdgcn_global_load_lds( \
    (const __attribute__((address_space(1))) void*)(g), \
    (__attribute__((address_space(3))) void*)(l), 16, 0, 0)

// ============================================================
// Phase 0: fp32 -> bf16 conversion (4 elements / thread)
// ============================================================
__global__ __launch_bounds__(256) void cvt_k(const float* __restrict__ src,
                                             u16* __restrict__ dst, int n4)
{
    const int i = blockIdx.x * blockDim.x + threadIdx.x;
    if (i < n4) {
        const f32x4 v = ((const f32x4*)src)[i];
        short4v o;
        o.x = (short)f2b(v.x); o.y = (short)f2b(v.y);
        o.z = (short)f2b(v.z); o.w = (short)f2b(v.w);
        ((short4v*)dst)[i] = o;
    }
}

// ============================================================
// Phase 1a: fused GEMM  C = X · W^T  for W in {Wk, Wv, Wq} (bf16 in, bf16 out)
// X: [16384, 1024]; W: [3072, 1024] (3 stacked); out: 3 x [16384, 1024]
// Tiles: BM=128, BN=128, BK=64; 256 threads = 4 waves (2x2 of 64x64)
// ============================================================
__global__ __launch_bounds__(256) void gemm_kvq(
    const u16* __restrict__ X, const u16* __restrict__ Wbf,
    u16* __restrict__ Ko, u16* __restrict__ Vo, u16* __restrict__ Qo)
{
    __shared__ u16 As[128 * 64];  // row-major, row stride 64 elems (128B)
    __shared__ u16 Bs[128 * 64];

    const int bm = blockIdx.x;            // 0..127  (M tiles)
    const int bn = blockIdx.y;            // 0..23   (N tiles over 3072)
    const int widx = bn >> 3;             // which W (tiles never straddle)
    const int n0 = (bn & 7) * 128;        // col base within 1024
    const u16* W = Wbf + (long)widx * 1048576;
    u16* O = (widx == 0) ? Ko : (widx == 1 ? Vo : Qo);

    const int tid = threadIdx.x;
    const int wave = tid >> 6;
    const int lane = tid & 63;

    const int srow = lane >> 3;           // 0..7 row within 1KB chunk
    const int scol = (lane & 7) * 8;      // element col offset within row

    const int wm = (wave & 1) * 64;
    const int wn = (wave >> 1) * 64;
    const int qd = lane >> 4;
    const int ln = lane & 15;

    f32x4 acc[4][4];
#pragma unroll
    for (int i = 0; i < 4; i++)
#pragma unroll
        for (int j = 0; j < 4; j++) acc[i][j] = (f32x4){0.f, 0.f, 0.f, 0.f};

    for (int k0 = 0; k0 < 1024; k0 += 64) {
        __syncthreads();  // prev-iter LDS reads done
#pragma unroll
        for (int c = 0; c < 4; c++) {
            const int chunk = wave * 4 + c;      // 0..15, 1KB each
            const int row = chunk * 8 + srow;    // tile row 0..127
            const u16* ga = X + (long)(bm * 128 + row) * 1024 + k0 + scol;
            GLDS(ga, &As[chunk * 512]);
            const u16* gb = W + (long)(n0 + row) * 1024 + k0 + scol;
            GLDS(gb, &Bs[chunk * 512]);
        }
        __syncthreads();  // drains vmcnt -> staged data visible
#pragma unroll
        for (int kk = 0; kk < 2; kk++) {
            short8 af[4], bf[4];
#pragma unroll
            for (int mt = 0; mt < 4; mt++)
                af[mt] = *(const short8*)&As[(wm + mt * 16 + ln) * 64 + kk * 32 + qd * 8];
#pragma unroll
            for (int nt = 0; nt < 4; nt++)
                bf[nt] = *(const short8*)&Bs[(wn + nt * 16 + ln) * 64 + kk * 32 + qd * 8];
#pragma unroll
            for (int mt = 0; mt < 4; mt++)
#pragma unroll
                for (int nt = 0; nt < 4; nt++)
                    acc[mt][nt] = __builtin_amdgcn_mfma_f32_16x16x32_bf16(
                        af[mt], bf[nt], acc[mt][nt], 0, 0, 0);
        }
    }

    // epilogue: C/D layout col=lane&15, row=quad*4+reg (verified m89/m91)
#pragma unroll
    for (int mt = 0; mt < 4; mt++) {
#pragma unroll
        for (int nt = 0; nt < 4; nt++) {
            const int r0 = bm * 128 + wm + mt * 16 + qd * 4;
            const int c = n0 + wn + nt * 16 + ln;
#pragma unroll
            for (int r = 0; r < 4; r++)
                O[(long)(r0 + r) * 1024 + c] = f2b(acc[mt][nt][r]);
        }
    }
}

// ============================================================
// Phase 1b: rn[m] = 1/(||k_row|| + eps), one wave per row (K is bf16)
// ============================================================
__global__ __launch_bounds__(256) void norm_k(const u16* __restrict__ K,
                                              float* __restrict__ rn)
{
    const int wave = threadIdx.x >> 6, lane = threadIdx.x & 63;
    const int row = blockIdx.x * 4 + wave;
    const u16* kr = K + (long)row * 1024;
    float s = 0.f;
#pragma unroll
    for (int i = 0; i < 16; i++) {
        float v = b2f(kr[lane + 64 * i]);
        s = fmaf(v, v, s);
    }
#pragma unroll
    for (int off = 1; off < 64; off <<= 1) s += __shfl_xor(s, off, 64);
    if (lane == 0) rn[row] = 1.0f / (sqrtf(s) + 1e-6f);
}

// ============================================================
// Phase 1c: per-row scalars S[m][0..7]=Vtk, [8..15]=k_r, [16..23]=Vtq
// One block (256 thr) per row m; thread = (j = tid&7, c = tid>>3)
// K,Q bf16; V0, Wkr fp32 (original inputs)
// ============================================================
__global__ __launch_bounds__(256) void scal_k(
    const u16* __restrict__ K, const u16* __restrict__ Q,
    const float* __restrict__ V0, const float* __restrict__ Wkr,
    const float* __restrict__ rn, float* __restrict__ S)
{
    const int m = blockIdx.x;
    const int b = m & 31;
    const int tid = threadIdx.x;
    const int j = tid & 7, c = tid >> 3;  // c: 0..31
    const u16* kp = K + (long)m * 1024;
    const u16* qp = Q + (long)m * 1024;
    const float* vp = V0 + (long)b * 8192;

    float avk = 0.f, akr = 0.f, avq = 0.f;
#pragma unroll 4
    for (int i = 0; i < 32; i++) {
        const int n = c + 32 * i;
        const float kv = b2f(kp[n]);
        const float qv = b2f(qp[n]);
        const float vj = vp[n * 8 + j];
        const float wj = Wkr[j * 1024 + n];
        avk = fmaf(vj, kv, avk);
        akr = fmaf(wj, kv, akr);
        avq = fmaf(vj, qv, avq);
    }
    // reduce over c within wave: lane = (c&7)*8 + j -> xor over {8,16,32}
#pragma unroll
    for (int off = 8; off < 64; off <<= 1) {
        avk += __shfl_xor(avk, off, 64);
        akr += __shfl_xor(akr, off, 64);
        avq += __shfl_xor(avq, off, 64);
    }
    __shared__ float red[4][3][8];
    const int wave = tid >> 6, lane = tid & 63;
    if (lane < 8) {  // c&7 == 0 -> lane == j
        red[wave][0][lane] = avk;
        red[wave][1][lane] = akr;
        red[wave][2][lane] = avq;
    }
    __syncthreads();
    if (tid < 24) {
        const int v = tid >> 3, jj = tid & 7;
        float s = red[0][v][jj] + red[1][v][jj] + red[2][v][jj] + red[3][v][jj];
        if (v != 2) s *= rn[m];  // Vtk and k_r use k_norm = k * rn
        S[(long)m * 32 + v * 8 + jj] = s;
    }
}

// ============================================================
// Phase 2: the scan. One thread per (b, n); U[8] in registers.
// Zero cross-thread communication; software-prefetch next step's
// v element (bf16) and 24-scalar fp32 row.
// ============================================================
__global__ __launch_bounds__(128) void scan_k(
    const u16* __restrict__ Vbuf, const float* __restrict__ S,
    const float* __restrict__ U0, float* __restrict__ outp,
    float* __restrict__ Ufin)
{
    const int b = blockIdx.x >> 3;
    const int n = (blockIdx.x & 7) * 128 + threadIdx.x;

    float U[8];
    const float* u0 = U0 + ((long)b * 1024 + n) * 8;
#pragma unroll
    for (int j = 0; j < 8; j++) U[j] = u0[j];

    // prefetch t = 0
    const f32x4* sp = (const f32x4*)(S + (long)b * 32);
    f32x4 vtk0 = sp[0], vtk1 = sp[1], kr0 = sp[2], kr1 = sp[3], vq0 = sp[4], vq1 = sp[5];
    float vv = b2f(Vbuf[(long)b * 1024 + n]);

    for (int t = 0; t < 512; t++) {
        const f32x4 a0 = vtk0, a1 = vtk1, K0 = kr0, K1 = kr1, Q0 = vq0, Q1 = vq1;
        const float vc = vv;
        // prefetch t+1 (clamped: last iter re-reads current row -- harmless)
        const int m2 = (t < 511) ? (t + 1) * 32 + b : t * 32 + b;
        const f32x4* sp2 = (const f32x4*)(S + (long)m2 * 32);
        vtk0 = sp2[0]; vtk1 = sp2[1]; kr0 = sp2[2]; kr1 = sp2[3]; vq0 = sp2[4]; vq1 = sp2[5];
        vv = b2f(Vbuf[(long)m2 * 1024 + n]);

        const float retrieved =
            U[0] * a0.x + U[1] * a0.y + U[2] * a0.z + U[3] * a0.w +
            U[4] * a1.x + U[5] * a1.y + U[6] * a1.z + U[7] * a1.w;
        const float delta = vc - retrieved;

        const float krj[8] = {K0.x, K0.y, K0.z, K0.w, K1.x, K1.y, K1.z, K1.w};
        const float vqj[8] = {Q0.x, Q0.y, Q0.z, Q0.w, Q1.x, Q1.y, Q1.z, Q1.w};

        float Sq = 0.f;
#pragma unroll
        for (int j = 0; j < 8; j++) {
            const float x = fmaf(delta, krj[j], U[j]);
            const float e = __expf(2.0f * x);                               // v_exp_f32 path
            const float u = 1.0f - 2.0f * __builtin_amdgcn_rcpf(e + 1.0f);  // tanh
            U[j] = u;
            Sq = fmaf(u, vqj[j], Sq);
        }
        const float sg = __builtin_amdgcn_rcpf(1.0f + __expf(-Sq));
        outp[(long)(t * 32 + b) * 1024 + n] = Sq * Sq * sg;  // Sq * silu(Sq)
    }

    // U_final, fp32, two 16B vector stores
    float* uf = Ufin + ((long)b * 1024 + n) * 8;
    ((f32x4*)uf)[0] = (f32x4){U[0], U[1], U[2], U[3]};
    ((f32x4*)uf)[1] = (f32x4){U[4], U[5], U[6], U[7]};
}

// ============================================================
// V output = V0 (unchanged); 16B-wide fp32 copy (262144 floats)
// ============================================================
__global__ __launch_bounds__(256) void vcopy_k(const float* __restrict__ src,
                                               float* __restrict__ dst)
{
    const int i = blockIdx.x * blockDim.x + threadIdx.x;  // 0..65535
    ((f32x4*)dst)[i] = ((const f32x4*)src)[i];
}

// ============================================================
extern "C" void kernel_launch(void* const* d_in, const int* in_sizes, int n_in,
                              void* d_out, int out_size, void* d_ws, size_t ws_size,
                              hipStream_t stream)
{
    const float* x   = (const float*)d_in[0];   // [512,32,1024]
    const float* Wk  = (const float*)d_in[1];   // [1024,1024]
    const float* Wv  = (const float*)d_in[2];
    const float* Wq  = (const float*)d_in[3];
    const float* Wkr = (const float*)d_in[4];   // [8,1024]
    const float* U0  = (const float*)d_in[5];   // [32,1024,8]
    const float* V0  = (const float*)d_in[6];   // [32,1024,8]
    float* out = (float*)d_out;                 // output(16777216) + U_final(262144) + V(262144)

    char* ws = (char*)d_ws;
    u16*   Xbf = (u16*)(ws);                    // 33,554,432 B
    u16*   Wbf = (u16*)(ws + 33554432);         //  6,291,456 B (Wk|Wv|Wq stacked)
    u16*   Kb  = (u16*)(ws + 39845888);         // 33,554,432 B
    u16*   Vb  = (u16*)(ws + 73400320);         // 33,554,432 B
    u16*   Qb  = (u16*)(ws + 106954752);        // 33,554,432 B
    float* rn  = (float*)(ws + 140509184);      //     65,536 B
    float* Sc  = (float*)(ws + 140574720);      //  2,097,152 B  (16384 x 32 f32)

    cvt_k<<<16384, 256, 0, stream>>>(x,  Xbf,               4194304);
    cvt_k<<<1024,  256, 0, stream>>>(Wk, Wbf,                262144);
    cvt_k<<<1024,  256, 0, stream>>>(Wv, Wbf + 1048576,      262144);
    cvt_k<<<1024,  256, 0, stream>>>(Wq, Wbf + 2097152,      262144);

    gemm_kvq<<<dim3(128, 24), 256, 0, stream>>>(Xbf, Wbf, Kb, Vb, Qb);
    norm_k  <<<4096, 256, 0, stream>>>(Kb, rn);
    scal_k  <<<16384, 256, 0, stream>>>(Kb, Qb, V0, Wkr, rn, Sc);
    scan_k  <<<256, 128, 0, stream>>>(Vb, Sc, U0, out, out + 16777216);
    vcopy_k <<<256, 256, 0, stream>>>(V0, out + 17039360);
}

// Round 3
// 570.779 us; speedup vs baseline: 1.2651x; 1.2651x over previous
//
#include <hip/hip_runtime.h>
#include <hip/hip_bf16.h>

typedef __attribute__((ext_vector_type(8))) short short8;
typedef __attribute__((ext_vector_type(4))) short short4v;
typedef __attribute__((ext_vector_type(4))) float f32x4;
typedef unsigned short u16;

// ---- bf16 helpers (bit-level, RNE) ----
__device__ inline float b2f(u16 u) {
    unsigned int i = ((unsigned int)u) << 16;
    float f; __builtin_memcpy(&f, &i, 4); return f;
}
__device__ inline u16 f2b(float f) {
    unsigned int i; __builtin_memcpy(&i, &f, 4);
    unsigned int r = (i + 0x7FFFu + ((i >> 16) & 1u)) >> 16;
    return (u16)r;
}

#define GLDS(g, l) __builtin_amdgcn_global_load_lds( \
    (const __attribute__((address_space(1))) void*)(g), \
    (__attribute__((address_space(3))) void*)(l), 16, 0, 0)

// ============================================================
// Phase 0: fp32 -> bf16 conversion (4 elements / thread)
// ============================================================
__global__ __launch_bounds__(256) void cvt_k(const float* __restrict__ src,
                                             u16* __restrict__ dst, int n4)
{
    const int i = blockIdx.x * blockDim.x + threadIdx.x;
    if (i < n4) {
        const f32x4 v = ((const f32x4*)src)[i];
        short4v o;
        o.x = (short)f2b(v.x); o.y = (short)f2b(v.y);
        o.z = (short)f2b(v.z); o.w = (short)f2b(v.w);
        ((short4v*)dst)[i] = o;
    }
}

// ============================================================
// Phase 1a: fused GEMM  C = X · W^T  for W in {Wk, Wv, Wq} (bf16 in, bf16 out)
// X: [16384, 1024]; W: [3072, 1024] (3 stacked); out: 3 x [16384, 1024]
// Tiles: BM=128, BN=128, BK=64; 256 threads = 4 waves (2x2 of 64x64)
// ============================================================
__global__ __launch_bounds__(256) void gemm_kvq(
    const u16* __restrict__ X, const u16* __restrict__ Wbf,
    u16* __restrict__ Ko, u16* __restrict__ Vo, u16* __restrict__ Qo)
{
    __shared__ u16 As[128 * 64];  // row-major, row stride 64 elems (128B)
    __shared__ u16 Bs[128 * 64];

    const int bm = blockIdx.x;            // 0..127  (M tiles)
    const int bn = blockIdx.y;            // 0..23   (N tiles over 3072)
    const int widx = bn >> 3;             // which W (tiles never straddle)
    const int n0 = (bn & 7) * 128;        // col base within 1024
    const u16* W = Wbf + (long)widx * 1048576;
    u16* O = (widx == 0) ? Ko : (widx == 1 ? Vo : Qo);

    const int tid = threadIdx.x;
    const int wave = tid >> 6;
    const int lane = tid & 63;

    const int srow = lane >> 3;           // 0..7 row within 1KB chunk
    const int scol = (lane & 7) * 8;      // element col offset within row

    const int wm = (wave & 1) * 64;
    const int wn = (wave >> 1) * 64;
    const int qd = lane >> 4;
    const int ln = lane & 15;

    f32x4 acc[4][4];
#pragma unroll
    for (int i = 0; i < 4; i++)
#pragma unroll
        for (int j = 0; j < 4; j++) acc[i][j] = (f32x4){0.f, 0.f, 0.f, 0.f};

    for (int k0 = 0; k0 < 1024; k0 += 64) {
        __syncthreads();  // prev-iter LDS reads done
#pragma unroll
        for (int c = 0; c < 4; c++) {
            const int chunk = wave * 4 + c;      // 0..15, 1KB each
            const int row = chunk * 8 + srow;    // tile row 0..127
            const u16* ga = X + (long)(bm * 128 + row) * 1024 + k0 + scol;
            GLDS(ga, &As[chunk * 512]);
            const u16* gb = W + (long)(n0 + row) * 1024 + k0 + scol;
            GLDS(gb, &Bs[chunk * 512]);
        }
        __syncthreads();  // drains vmcnt -> staged data visible
#pragma unroll
        for (int kk = 0; kk < 2; kk++) {
            short8 af[4], bf[4];
#pragma unroll
            for (int mt = 0; mt < 4; mt++)
                af[mt] = *(const short8*)&As[(wm + mt * 16 + ln) * 64 + kk * 32 + qd * 8];
#pragma unroll
            for (int nt = 0; nt < 4; nt++)
                bf[nt] = *(const short8*)&Bs[(wn + nt * 16 + ln) * 64 + kk * 32 + qd * 8];
#pragma unroll
            for (int mt = 0; mt < 4; mt++)
#pragma unroll
                for (int nt = 0; nt < 4; nt++)
                    acc[mt][nt] = __builtin_amdgcn_mfma_f32_16x16x32_bf16(
                        af[mt], bf[nt], acc[mt][nt], 0, 0, 0);
        }
    }

    // epilogue: C/D layout col=lane&15, row=quad*4+reg (verified m89/m91)
#pragma unroll
    for (int mt = 0; mt < 4; mt++) {
#pragma unroll
        for (int nt = 0; nt < 4; nt++) {
            const int r0 = bm * 128 + wm + mt * 16 + qd * 4;
            const int c = n0 + wn + nt * 16 + ln;
#pragma unroll
            for (int r = 0; r < 4; r++)
                O[(long)(r0 + r) * 1024 + c] = f2b(acc[mt][nt][r]);
        }
    }
}

// ============================================================
// Phase 1c (now also computes rn in-block): per-row scalars
//   S[b][t][0..7]=Vtk, [8..15]=k_r, [16..23]=Vtq   (layout [b][t][32])
// One block (256 thr) per row m = t*32+b; thread = (j = tid&7, c = tid>>3)
// K,Q bf16; V0, Wkr fp32 (original inputs)
// ============================================================
__global__ __launch_bounds__(256) void scal_k(
    const u16* __restrict__ K, const u16* __restrict__ Q,
    const float* __restrict__ V0, const float* __restrict__ Wkr,
    float* __restrict__ S)
{
    const int m = blockIdx.x;
    const int b = m & 31, t = m >> 5;
    const int tid = threadIdx.x;
    const int j = tid & 7, c = tid >> 3;  // c: 0..31
    const u16* kp = K + (long)m * 1024;
    const u16* qp = Q + (long)m * 1024;
    const float* vp = V0 + (long)b * 8192;

    float avk = 0.f, akr = 0.f, avq = 0.f, ass = 0.f;
#pragma unroll 4
    for (int i = 0; i < 32; i++) {
        const int n = c + 32 * i;
        const float kv = b2f(kp[n]);
        const float qv = b2f(qp[n]);
        const float vj = vp[n * 8 + j];
        const float wj = Wkr[j * 1024 + n];
        avk = fmaf(vj, kv, avk);
        akr = fmaf(wj, kv, akr);
        avq = fmaf(vj, qv, avq);
        ass = fmaf(kv, kv, ass);   // same value across the 8 j's of a c
    }
    // reduce over c within wave: lane = (c&7)*8 + j -> xor over {8,16,32}
#pragma unroll
    for (int off = 8; off < 64; off <<= 1) {
        avk += __shfl_xor(avk, off, 64);
        akr += __shfl_xor(akr, off, 64);
        avq += __shfl_xor(avq, off, 64);
        ass += __shfl_xor(ass, off, 64);
    }
    __shared__ float red[4][3][8];
    __shared__ float ssr[4];
    __shared__ float rnv;
    const int wave = tid >> 6, lane = tid & 63;
    if (lane == 0) ssr[wave] = ass;     // partial ||k||^2 over this wave's c's
    if (lane < 8) {  // c&7 == 0 -> lane == j
        red[wave][0][lane] = avk;
        red[wave][1][lane] = akr;
        red[wave][2][lane] = avq;
    }
    __syncthreads();
    if (tid == 0)
        rnv = 1.0f / (sqrtf(ssr[0] + ssr[1] + ssr[2] + ssr[3]) + 1e-6f);
    __syncthreads();
    if (tid < 24) {
        const int v = tid >> 3, jj = tid & 7;
        float s = red[0][v][jj] + red[1][v][jj] + red[2][v][jj] + red[3][v][jj];
        if (v != 2) s *= rnv;  // Vtk and k_r use k_norm = k * rn
        S[((long)b * 512 + t) * 32 + v * 8 + jj] = s;
    }
}

// ============================================================
// Phase 2: the scan. One thread per (b, n); U[8] in registers.
// S staged to LDS (64KB/block), depth-2 register pipeline on S,
// 16-step-deep prefetch on V.
// ============================================================
__global__ __launch_bounds__(128) void scan_k(
    const u16* __restrict__ Vbuf, const float* __restrict__ S,
    const float* __restrict__ U0, float* __restrict__ outp,
    float* __restrict__ Ufin)
{
    __shared__ float Sl[512 * 32];  // 64 KB

    const int b = blockIdx.x >> 3;
    const int n = (blockIdx.x & 7) * 128 + threadIdx.x;

    // stage S[b] (coalesced: contiguous 64KB in [b][t][32] layout)
    {
        const f32x4* Sg = (const f32x4*)(S + (long)b * 16384);
        f32x4* Sd = (f32x4*)Sl;
        for (int i = threadIdx.x; i < 4096; i += 128) Sd[i] = Sg[i];
    }

    float U[8];
    {
        const float* u0 = U0 + ((long)b * 1024 + n) * 8;
#pragma unroll
        for (int j = 0; j < 8; j++) U[j] = u0[j];
    }

    // V prefetch: group of 16 t's, one group ahead (coalesced across wave)
    const u16* vp0 = Vbuf + (long)b * 1024 + n;   // + t*32768
    u16 vnx[16];
#pragma unroll
    for (int i = 0; i < 16; i++) vnx[i] = vp0[(long)i * 32768];

    __syncthreads();  // S staged

    // S pipeline prologue: sc = step 0, sn = step 1
    f32x4 sc[6], sn[6];
#pragma unroll
    for (int r = 0; r < 6; r++) sc[r] = *(const f32x4*)&Sl[r * 4];
#pragma unroll
    for (int r = 0; r < 6; r++) sn[r] = *(const f32x4*)&Sl[32 + r * 4];

    float* op = outp + (long)b * 1024 + n;   // + t*32768

    for (int t0 = 0; t0 < 512; t0 += 16) {
        // decode current group's v (loads issued one group ago)
        float vcur[16];
#pragma unroll
        for (int i = 0; i < 16; i++) vcur[i] = b2f(vnx[i]);
        // issue next group's v loads (clamped tail re-read, values unused)
        const int tn = (t0 + 16 < 512) ? (t0 + 16) : t0;
#pragma unroll
        for (int i = 0; i < 16; i++) vnx[i] = vp0[(long)(tn + i) * 32768];

#pragma unroll
        for (int i = 0; i < 16; i++) {
            const int t = t0 + i;
            // issue LDS reads for step t+2
            const int tf = (t + 2 < 512) ? (t + 2) : t;
            f32x4 sm[6];
#pragma unroll
            for (int r = 0; r < 6; r++) sm[r] = *(const f32x4*)&Sl[tf * 32 + r * 4];

            const f32x4 a0 = sc[0], a1 = sc[1], K0 = sc[2], K1 = sc[3],
                        Q0 = sc[4], Q1 = sc[5];
            // rotate pipeline (SSA renaming — no real copies after unroll)
#pragma unroll
            for (int r = 0; r < 6; r++) { sc[r] = sn[r]; sn[r] = sm[r]; }

            const float vc = vcur[i];
            const float retrieved =
                U[0] * a0.x + U[1] * a0.y + U[2] * a0.z + U[3] * a0.w +
                U[4] * a1.x + U[5] * a1.y + U[6] * a1.z + U[7] * a1.w;
            const float delta = vc - retrieved;

            const float krj[8] = {K0.x, K0.y, K0.z, K0.w, K1.x, K1.y, K1.z, K1.w};
            const float vqj[8] = {Q0.x, Q0.y, Q0.z, Q0.w, Q1.x, Q1.y, Q1.z, Q1.w};

            float Sq = 0.f;
#pragma unroll
            for (int j = 0; j < 8; j++) {
                const float x = fmaf(delta, krj[j], U[j]);
                const float e = __expf(2.0f * x);                               // v_exp_f32
                const float u = 1.0f - 2.0f * __builtin_amdgcn_rcpf(e + 1.0f);  // tanh
                U[j] = u;
                Sq = fmaf(u, vqj[j], Sq);
            }
            const float sg = __builtin_amdgcn_rcpf(1.0f + __expf(-Sq));
            op[(long)t * 32768] = Sq * Sq * sg;  // Sq * silu(Sq)
        }
    }

    // U_final, fp32, two 16B vector stores
    float* uf = Ufin + ((long)b * 1024 + n) * 8;
    ((f32x4*)uf)[0] = (f32x4){U[0], U[1], U[2], U[3]};
    ((f32x4*)uf)[1] = (f32x4){U[4], U[5], U[6], U[7]};
}

// ============================================================
// V output = V0 (unchanged); 16B-wide fp32 copy (262144 floats)
// ============================================================
__global__ __launch_bounds__(256) void vcopy_k(const float* __restrict__ src,
                                               float* __restrict__ dst)
{
    const int i = blockIdx.x * blockDim.x + threadIdx.x;  // 0..65535
    ((f32x4*)dst)[i] = ((const f32x4*)src)[i];
}

// ============================================================
extern "C" void kernel_launch(void* const* d_in, const int* in_sizes, int n_in,
                              void* d_out, int out_size, void* d_ws, size_t ws_size,
                              hipStream_t stream)
{
    const float* x   = (const float*)d_in[0];   // [512,32,1024]
    const float* Wk  = (const float*)d_in[1];   // [1024,1024]
    const float* Wv  = (const float*)d_in[2];
    const float* Wq  = (const float*)d_in[3];
    const float* Wkr = (const float*)d_in[4];   // [8,1024]
    const float* U0  = (const float*)d_in[5];   // [32,1024,8]
    const float* V0  = (const float*)d_in[6];   // [32,1024,8]
    float* out = (float*)d_out;                 // output(16777216) + U_final(262144) + V(262144)

    char* ws = (char*)d_ws;
    u16*   Xbf = (u16*)(ws);                    // 33,554,432 B
    u16*   Wbf = (u16*)(ws + 33554432);         //  6,291,456 B (Wk|Wv|Wq stacked)
    u16*   Kb  = (u16*)(ws + 39845888);         // 33,554,432 B
    u16*   Vb  = (u16*)(ws + 73400320);         // 33,554,432 B
    u16*   Qb  = (u16*)(ws + 106954752);        // 33,554,432 B
    float* Sc  = (float*)(ws + 140509184);      //  2,097,152 B  (32 x 512 x 32 f32)

    cvt_k<<<16384, 256, 0, stream>>>(x,  Xbf,               4194304);
    cvt_k<<<1024,  256, 0, stream>>>(Wk, Wbf,                262144);
    cvt_k<<<1024,  256, 0, stream>>>(Wv, Wbf + 1048576,      262144);
    cvt_k<<<1024,  256, 0, stream>>>(Wq, Wbf + 2097152,      262144);

    gemm_kvq<<<dim3(128, 24), 256, 0, stream>>>(Xbf, Wbf, Kb, Vb, Qb);
    scal_k  <<<16384, 256, 0, stream>>>(Kb, Qb, V0, Wkr, Sc);
    scan_k  <<<256, 128, 0, stream>>>(Vb, Sc, U0, out, out + 16777216);
    vcopy_k <<<256, 256, 0, stream>>>(V0, out + 17039360);
}

// Round 4
// 436.633 us; speedup vs baseline: 1.6537x; 1.3072x over previous
//
#include <hip/hip_runtime.h>
#include <hip/hip_bf16.h>

typedef __attribute__((ext_vector_type(8))) short short8;
typedef __attribute__((ext_vector_type(4))) short short4v;
typedef __attribute__((ext_vector_type(4))) float f32x4;
typedef unsigned short u16;

// ---- bf16 helpers (bit-level, RNE) ----
__device__ inline float b2f(u16 u) {
    unsigned int i = ((unsigned int)u) << 16;
    float f; __builtin_memcpy(&f, &i, 4); return f;
}
__device__ inline u16 f2b(float f) {
    unsigned int i; __builtin_memcpy(&i, &f, 4);
    unsigned int r = (i + 0x7FFFu + ((i >> 16) & 1u)) >> 16;
    return (u16)r;
}

#define GLDS(g, l) __builtin_amdgcn_global_load_lds( \
    (const __attribute__((address_space(1))) void*)(g), \
    (__attribute__((address_space(3))) void*)(l), 16, 0, 0)

// ============================================================
// Phase 0: fp32 -> bf16 conversion (4 elements / thread)
// ============================================================
__global__ __launch_bounds__(256) void cvt_k(const float* __restrict__ src,
                                             u16* __restrict__ dst, int n4)
{
    const int i = blockIdx.x * blockDim.x + threadIdx.x;
    if (i < n4) {
        const f32x4 v = ((const f32x4*)src)[i];
        short4v o;
        o.x = (short)f2b(v.x); o.y = (short)f2b(v.y);
        o.z = (short)f2b(v.z); o.w = (short)f2b(v.w);
        ((short4v*)dst)[i] = o;
    }
}

// ============================================================
// Phase 0b: V0 transpose  V0T[b][j][n] = V0[b][n][j]  (fp32, 1 MB)
// 64 blocks x 256 thr; thread = (b, j, n-chunk of 16)
// ============================================================
__global__ __launch_bounds__(256) void vT_k(const float* __restrict__ V0,
                                            float* __restrict__ V0T)
{
    const int gid = blockIdx.x * 256 + threadIdx.x;   // 0..16383
    const int b = gid >> 9, j = (gid >> 6) & 7, n0 = (gid & 63) * 16;
    const float* src = V0 + (long)b * 8192 + (long)n0 * 8 + j;
    float* dst = V0T + (long)b * 8192 + (long)j * 1024 + n0;
#pragma unroll
    for (int i = 0; i < 16; i += 4) {
        f32x4 o = { src[(i + 0) * 8], src[(i + 1) * 8],
                    src[(i + 2) * 8], src[(i + 3) * 8] };
        *(f32x4*)(dst + i) = o;
    }
}

// ============================================================
// Phase 1a: fused GEMM  C = X · W^T, XOR-swizzled LDS (bank-conflict-free)
// X: [16384, 1024]; W: [3072, 1024] (3 stacked); out: 3 x [16384, 1024]
// Tiles: BM=128, BN=128, BK=64; 256 threads = 4 waves (2x2 of 64x64)
// LDS layout: row r (stride 64 elems = 128 B); within row, physical 16B
// block p holds global col-block p ^ (r&7).
// ============================================================
__global__ __launch_bounds__(256) void gemm_kvq(
    const u16* __restrict__ X, const u16* __restrict__ Wbf,
    u16* __restrict__ Ko, u16* __restrict__ Vo, u16* __restrict__ Qo)
{
    __shared__ u16 As[128 * 64];
    __shared__ u16 Bs[128 * 64];

    const int bm = blockIdx.x;            // 0..127  (M tiles)
    const int bn = blockIdx.y;            // 0..23   (N tiles over 3072)
    const int widx = bn >> 3;
    const int n0 = (bn & 7) * 128;
    const u16* W = Wbf + (long)widx * 1048576;
    u16* O = (widx == 0) ? Ko : (widx == 1 ? Vo : Qo);

    const int tid = threadIdx.x;
    const int wave = tid >> 6;
    const int lane = tid & 63;

    const int srow = lane >> 3;                     // 0..7 row within 1KB chunk
    const int scol = ((lane & 7) ^ srow) * 8;       // swizzled source col block

    const int wm = (wave & 1) * 64;
    const int wn = (wave >> 1) * 64;
    const int qd = lane >> 4;
    const int ln = lane & 15;
    const int lx = ln & 7;                          // row&7 for swizzle

    f32x4 acc[4][4];
#pragma unroll
    for (int i = 0; i < 4; i++)
#pragma unroll
        for (int j = 0; j < 4; j++) acc[i][j] = (f32x4){0.f, 0.f, 0.f, 0.f};

    for (int k0 = 0; k0 < 1024; k0 += 64) {
        __syncthreads();  // prev-iter LDS reads done
#pragma unroll
        for (int c = 0; c < 4; c++) {
            const int chunk = wave * 4 + c;      // 0..15, 1KB each
            const int row = chunk * 8 + srow;    // tile row 0..127
            const u16* ga = X + (long)(bm * 128 + row) * 1024 + k0 + scol;
            GLDS(ga, &As[chunk * 512]);
            const u16* gb = W + (long)(n0 + row) * 1024 + k0 + scol;
            GLDS(gb, &Bs[chunk * 512]);
        }
        __syncthreads();  // drains vmcnt -> staged data visible
#pragma unroll
        for (int kk = 0; kk < 2; kk++) {
            short8 af[4], bf[4];
#pragma unroll
            for (int mt = 0; mt < 4; mt++)
                af[mt] = *(const short8*)&As[(wm + mt * 16 + ln) * 64 +
                                             (((kk * 4 + qd) ^ lx) * 8)];
#pragma unroll
            for (int nt = 0; nt < 4; nt++)
                bf[nt] = *(const short8*)&Bs[(wn + nt * 16 + ln) * 64 +
                                             (((kk * 4 + qd) ^ lx) * 8)];
#pragma unroll
            for (int mt = 0; mt < 4; mt++)
#pragma unroll
                for (int nt = 0; nt < 4; nt++)
                    acc[mt][nt] = __builtin_amdgcn_mfma_f32_16x16x32_bf16(
                        af[mt], bf[nt], acc[mt][nt], 0, 0, 0);
        }
    }

    // epilogue: C/D layout col=lane&15, row=quad*4+reg (verified m89/m91)
#pragma unroll
    for (int mt = 0; mt < 4; mt++) {
#pragma unroll
        for (int nt = 0; nt < 4; nt++) {
            const int r0 = bm * 128 + wm + mt * 16 + qd * 4;
            const int c = n0 + wn + nt * 16 + ln;
#pragma unroll
            for (int r = 0; r < 4; r++)
                O[(long)(r0 + r) * 1024 + c] = f2b(acc[mt][nt][r]);
        }
    }
}

// ============================================================
// Phase 1c: per-row scalars, 4 t's per block.
//   S[b][t][0..7]=Vtk_u*rn, [8..15]=k_r_u*rn, [16..23]=Vtq
// Block = (b, t-group of 4); thread = (j = tid&7, c = tid>>3), n = c*32..+31
// K,Q bf16 (contiguous b128); V0T, Wkr fp32 (contiguous f32x4, L2-resident)
// ============================================================
__global__ __launch_bounds__(256) void scal_k(
    const u16* __restrict__ K, const u16* __restrict__ Q,
    const float* __restrict__ V0T, const float* __restrict__ Wkr,
    float* __restrict__ S)
{
    const int b  = blockIdx.x & 31;
    const int t0 = (blockIdx.x >> 5) * 4;
    const int tid = threadIdx.x;
    const int j = tid & 7, c = tid >> 3;      // c: 0..31
    const int n0 = c * 32;

    f32x4 vv[8], ww[8];
    {
        const f32x4* vp = (const f32x4*)(V0T + (long)b * 8192 + (long)j * 1024 + n0);
        const f32x4* wp = (const f32x4*)(Wkr + (long)j * 1024 + n0);
#pragma unroll
        for (int i = 0; i < 8; i++) { vv[i] = vp[i]; ww[i] = wp[i]; }
    }

    float avk[4], akr[4], avq[4], ass[4];
#pragma unroll
    for (int dt = 0; dt < 4; dt++) { avk[dt] = akr[dt] = avq[dt] = ass[dt] = 0.f; }

#pragma unroll
    for (int dt = 0; dt < 4; dt++) {
        const long m = (long)(t0 + dt) * 32 + b;
        const short8* kp = (const short8*)(K + m * 1024 + n0);
        const short8* qp = (const short8*)(Q + m * 1024 + n0);
#pragma unroll
        for (int i = 0; i < 4; i++) {
            const short8 kb = kp[i], qb = qp[i];
#pragma unroll
            for (int e = 0; e < 8; e++) {
                const int idx = i * 8 + e;
                const float kv = b2f((u16)kb[e]);
                const float qv = b2f((u16)qb[e]);
                const float vj = vv[idx >> 2][idx & 3];
                const float wj = ww[idx >> 2][idx & 3];
                avk[dt] = fmaf(vj, kv, avk[dt]);
                akr[dt] = fmaf(wj, kv, akr[dt]);
                avq[dt] = fmaf(vj, qv, avq[dt]);
                ass[dt] = fmaf(kv, kv, ass[dt]);
            }
        }
    }

    __shared__ float red[4][4][3][8];   // [wave][dt][v][j]
    __shared__ float ssr[4][4];         // [wave][dt]
    const int wave = tid >> 6, lane = tid & 63;
#pragma unroll
    for (int dt = 0; dt < 4; dt++) {
        float a = avk[dt], k2 = akr[dt], q = avq[dt], s = ass[dt];
#pragma unroll
        for (int off = 8; off < 64; off <<= 1) {
            a  += __shfl_xor(a,  off, 64);
            k2 += __shfl_xor(k2, off, 64);
            q  += __shfl_xor(q,  off, 64);
            s  += __shfl_xor(s,  off, 64);
        }
        if (lane < 8) {
            red[wave][dt][0][lane] = a;
            red[wave][dt][1][lane] = k2;
            red[wave][dt][2][lane] = q;
        }
        if (lane == 0) ssr[wave][dt] = s;
    }
    __syncthreads();
    if (tid < 128) {
        const int dt = tid >> 5, rr = tid & 31;
        if (rr < 24) {
            const int v = rr >> 3, jj = rr & 7;
            float s = red[0][dt][v][jj] + red[1][dt][v][jj] +
                      red[2][dt][v][jj] + red[3][dt][v][jj];
            if (v != 2) {
                const float n2 = ssr[0][dt] + ssr[1][dt] + ssr[2][dt] + ssr[3][dt];
                s *= 1.0f / (sqrtf(n2) + 1e-6f);
            }
            S[((long)b * 512 + t0 + dt) * 32 + v * 8 + jj] = s;
        }
    }
}

// ============================================================
// Phase 2: the scan, r-split x2. Thread = (b, n, r-half); U[4] each.
// Pair at lane^32 exchanges dot-product partials (2 shuffles/step).
// 512 blocks x 128 thr -> 4 waves/CU; S[b] in LDS (64KB), depth-2
// register pipeline on S; 16-step-deep global prefetch on V.
// ============================================================
__global__ __launch_bounds__(128) void scan_k(
    const u16* __restrict__ Vbuf, const float* __restrict__ S,
    const float* __restrict__ U0, float* __restrict__ outp,
    float* __restrict__ Ufin)
{
    __shared__ float Sl[512 * 32];  // 64 KB

    const int b = blockIdx.x >> 4;
    const int chunk = blockIdx.x & 15;          // n-chunk of 64
    const int wave = threadIdx.x >> 6, lane = threadIdx.x & 63;
    const int rh = lane >> 5;                   // r-half (0: r0..3, 1: r4..7)
    const int n = chunk * 64 + wave * 32 + (lane & 31);
    const int so = rh * 4;

    // stage S[b] (coalesced, contiguous 64KB)
    {
        const f32x4* Sg = (const f32x4*)(S + (long)b * 16384);
        f32x4* Sd = (f32x4*)Sl;
        for (int i = threadIdx.x; i < 4096; i += 128) Sd[i] = Sg[i];
    }

    float U[4];
    {
        const float* u0 = U0 + ((long)b * 1024 + n) * 8 + so;
#pragma unroll
        for (int j2 = 0; j2 < 4; j2++) U[j2] = u0[j2];
    }

    const u16* vp0 = Vbuf + (long)b * 1024 + n;
    u16 vnx[16];
#pragma unroll
    for (int i = 0; i < 16; i++) vnx[i] = vp0[(long)i * 32768];

    __syncthreads();  // S staged

    f32x4 sc[3], sn[3];
#pragma unroll
    for (int r = 0; r < 3; r++) sc[r] = *(const f32x4*)&Sl[r * 8 + so];
#pragma unroll
    for (int r = 0; r < 3; r++) sn[r] = *(const f32x4*)&Sl[32 + r * 8 + so];

    float* op = outp + (long)b * 1024 + n;

    for (int t0 = 0; t0 < 512; t0 += 16) {
        float vcur[16];
#pragma unroll
        for (int i = 0; i < 16; i++) vcur[i] = b2f(vnx[i]);
        const int tn = (t0 + 16 < 512) ? (t0 + 16) : t0;
#pragma unroll
        for (int i = 0; i < 16; i++) vnx[i] = vp0[(long)(tn + i) * 32768];

#pragma unroll
        for (int i = 0; i < 16; i++) {
            const int t = t0 + i;
            const int tf = (t + 2 < 512) ? (t + 2) : t;
            f32x4 sm[3];
#pragma unroll
            for (int r = 0; r < 3; r++) sm[r] = *(const f32x4*)&Sl[tf * 32 + r * 8 + so];

            const f32x4 a = sc[0], Kk = sc[1], Qq = sc[2];
#pragma unroll
            for (int r = 0; r < 3; r++) { sc[r] = sn[r]; sn[r] = sm[r]; }

            // retrieved: tree + cross-half exchange
            float pr = fmaf(U[0], a.x, U[1] * a.y) + fmaf(U[2], a.z, U[3] * a.w);
            const float ret = pr + __shfl_xor(pr, 32, 64);
            const float delta = vcur[i] - ret;

            const float kr4[4] = {Kk.x, Kk.y, Kk.z, Kk.w};
            const float vq4[4] = {Qq.x, Qq.y, Qq.z, Qq.w};

            float sq0 = 0.f, sq1 = 0.f;
#pragma unroll
            for (int j2 = 0; j2 < 4; j2++) {
                const float x = fmaf(delta, kr4[j2], U[j2]);
                const float e = __expf(2.0f * x);                               // v_exp_f32
                const float u = 1.0f - 2.0f * __builtin_amdgcn_rcpf(e + 1.0f);  // tanh
                U[j2] = u;
                if (j2 & 1) sq1 = fmaf(u, vq4[j2], sq1);
                else        sq0 = fmaf(u, vq4[j2], sq0);
            }
            const float sqp = sq0 + sq1;
            const float Sq = sqp + __shfl_xor(sqp, 32, 64);
            const float sg = __builtin_amdgcn_rcpf(1.0f + __expf(-Sq));
            const float o = Sq * Sq * sg;  // Sq * silu(Sq)
            if (rh == 0) op[(long)t * 32768] = o;
        }
    }

    // U_final: each thread stores its 4 (16B aligned)
    *(f32x4*)(Ufin + ((long)b * 1024 + n) * 8 + so) = (f32x4){U[0], U[1], U[2], U[3]};
}

// ============================================================
// V output = V0 (unchanged); 16B-wide fp32 copy (262144 floats)
// ============================================================
__global__ __launch_bounds__(256) void vcopy_k(const float* __restrict__ src,
                                               float* __restrict__ dst)
{
    const int i = blockIdx.x * blockDim.x + threadIdx.x;  // 0..65535
    ((f32x4*)dst)[i] = ((const f32x4*)src)[i];
}

// ============================================================
extern "C" void kernel_launch(void* const* d_in, const int* in_sizes, int n_in,
                              void* d_out, int out_size, void* d_ws, size_t ws_size,
                              hipStream_t stream)
{
    const float* x   = (const float*)d_in[0];   // [512,32,1024]
    const float* Wk  = (const float*)d_in[1];   // [1024,1024]
    const float* Wv  = (const float*)d_in[2];
    const float* Wq  = (const float*)d_in[3];
    const float* Wkr = (const float*)d_in[4];   // [8,1024]
    const float* U0  = (const float*)d_in[5];   // [32,1024,8]
    const float* V0  = (const float*)d_in[6];   // [32,1024,8]
    float* out = (float*)d_out;                 // output(16777216) + U_final(262144) + V(262144)

    char* ws = (char*)d_ws;
    u16*   Xbf = (u16*)(ws);                    // 33,554,432 B
    u16*   Wbf = (u16*)(ws + 33554432);         //  6,291,456 B (Wk|Wv|Wq stacked)
    u16*   Kb  = (u16*)(ws + 39845888);         // 33,554,432 B
    u16*   Vb  = (u16*)(ws + 73400320);         // 33,554,432 B
    u16*   Qb  = (u16*)(ws + 106954752);        // 33,554,432 B
    float* Sc  = (float*)(ws + 140509184);      //  2,097,152 B  (32 x 512 x 32 f32)
    float* V0T = (float*)(ws + 142606336);      //  1,048,576 B  (32 x 8 x 1024 f32)

    cvt_k<<<16384, 256, 0, stream>>>(x,  Xbf,               4194304);
    cvt_k<<<1024,  256, 0, stream>>>(Wk, Wbf,                262144);
    cvt_k<<<1024,  256, 0, stream>>>(Wv, Wbf + 1048576,      262144);
    cvt_k<<<1024,  256, 0, stream>>>(Wq, Wbf + 2097152,      262144);
    vT_k <<<64,    256, 0, stream>>>(V0, V0T);

    gemm_kvq<<<dim3(128, 24), 256, 0, stream>>>(Xbf, Wbf, Kb, Vb, Qb);
    scal_k  <<<4096, 256, 0, stream>>>(Kb, Qb, V0T, Wkr, Sc);
    scan_k  <<<512, 128, 0, stream>>>(Vb, Sc, U0, out, out + 16777216);
    vcopy_k <<<256, 256, 0, stream>>>(V0, out + 17039360);
}